// Round 1
// baseline (266.907 us; speedup 1.0000x reference)
//
#include <hip/hip_runtime.h>
#include <hip/hip_bf16.h>
#include <cstdint>
#include <cstddef>

// ---------------------------------------------------------------------------
// YiJingAttention: x[B,T,C] -> qkv -> causal attn (+rank-1 trigram bias) -> out
// B=2 T=2048 C=1024 H=8 hd=128. All internal matmuls in bf16 MFMA, f32 accum.
// ---------------------------------------------------------------------------

namespace {
constexpr int kB = 2, kT = 2048, kC = 1024, kHD = 128;
constexpr int kM = kB * kT;   // 4096 rows
constexpr int kN3 = 3 * kC;   // 3072
constexpr float kScale = 0.08838834764831845f;   // 1/sqrt(128)
constexpr float kInvS3 = 0.57735026918962576f;   // 1/sqrt(3)
constexpr float kL2E  = 1.4426950408889634f;     // log2(e)
}

typedef __bf16 bf16x8 __attribute__((ext_vector_type(8)));
typedef float f32x4 __attribute__((ext_vector_type(4)));
typedef unsigned short u16x8 __attribute__((ext_vector_type(8)));
typedef unsigned short u16x4 __attribute__((ext_vector_type(4)));

__device__ __forceinline__ unsigned short f2b(float f) {
  return __builtin_bit_cast(unsigned short, (__bf16)f);
}
__device__ __forceinline__ float b2f(unsigned short u) {
  return (float)__builtin_bit_cast(__bf16, u);
}
// async global->LDS, 16B per lane. lds must be wave-uniform base (HW adds lane*16).
__device__ __forceinline__ void gll16(const void* g, void* lds) {
  __builtin_amdgcn_global_load_lds(
      (const __attribute__((address_space(1))) unsigned int*)g,
      (__attribute__((address_space(3))) unsigned int*)lds, 16, 0, 0);
}
__device__ __forceinline__ bf16x8 ldsv(const unsigned short* p) {
  return __builtin_bit_cast(bf16x8, *(const u16x8*)p);
}

// -------------------------- fp32 -> bf16 cast ------------------------------
__global__ void k_cvt(const float* __restrict__ in, unsigned short* __restrict__ out, int n4) {
  int i = blockIdx.x * 256 + threadIdx.x;
  if (i >= n4) return;
  float4 v = ((const float4*)in)[i];
  u16x4 o = { f2b(v.x), f2b(v.y), f2b(v.z), f2b(v.w) };
  ((u16x4*)out)[i] = o;
}

// ------------------- transpose + cast: in[R][Cin]f32 -> out[Cin][R]bf16 ----
__global__ void k_tc(const float* __restrict__ in, unsigned short* __restrict__ out,
                     int R, int Cin) {
  __shared__ float tile[64][65];
  const int t = threadIdx.x;
  const int r0 = blockIdx.y * 64, c0 = blockIdx.x * 64;
  const int tr = t >> 4, tc4 = (t & 15) * 4;
#pragma unroll
  for (int rr = 0; rr < 4; ++rr) {
    int r = tr + rr * 16;
    float4 v = *(const float4*)&in[(size_t)(r0 + r) * Cin + c0 + tc4];
    tile[r][tc4 + 0] = v.x; tile[r][tc4 + 1] = v.y;
    tile[r][tc4 + 2] = v.z; tile[r][tc4 + 3] = v.w;
  }
  __syncthreads();
#pragma unroll
  for (int rr = 0; rr < 4; ++rr) {
    int c = tr + rr * 16;
    u16x4 o = { f2b(tile[tc4 + 0][c]), f2b(tile[tc4 + 1][c]),
                f2b(tile[tc4 + 2][c]), f2b(tile[tc4 + 3][c]) };
    *(u16x4*)&out[(size_t)(c0 + c) * R + r0 + tc4] = o;
  }
}

// ----------------- 128x128 bf16 MFMA GEMM, Bt is [N][K] --------------------
// C = A[M,K] @ Bt^T. Writes bf16 (Cb) or f32 (Cf).
__global__ __launch_bounds__(256, 2) void k_gemm(
    const unsigned short* __restrict__ A,
    const unsigned short* __restrict__ Bt,
    unsigned short* __restrict__ Cb,
    float* __restrict__ Cf,
    int M, int N, int K, int ldc) {
  __shared__ unsigned short sA[2][4096];   // 128 rows x 32 k (swizzled groups)
  __shared__ unsigned short sB[2][4096];
  const int t = threadIdx.x;
  const int lane = t & 63, wave = t >> 6;
  const int g = lane >> 4, c16 = lane & 15;
  const int wr = wave >> 1, wc = wave & 1;
  const int brow = blockIdx.x * 128, bcol = blockIdx.y * 128;
  const int NT = K >> 5;

  f32x4 acc[4][4];
#pragma unroll
  for (int m = 0; m < 4; ++m)
#pragma unroll
    for (int n = 0; n < 4; ++n) acc[m][n] = 0.f;

  auto stage = [&](int buf, int kt) {
    const int k0 = kt * 32;
#pragma unroll
    for (int is = 0; is < 2; ++is) {
      int row = is * 64 + (t >> 2);
      int gs = (t & 3) ^ (row & 3);          // pre-swizzled source group
      gll16(&A[(size_t)(brow + row) * K + k0 + gs * 8], &sA[buf][is * 2048 + wave * 512]);
      gll16(&Bt[(size_t)(bcol + row) * K + k0 + gs * 8], &sB[buf][is * 2048 + wave * 512]);
    }
  };

  stage(0, 0);
  __syncthreads();
  for (int kt = 0; kt < NT; ++kt) {
    if (kt + 1 < NT) stage((kt + 1) & 1, kt + 1);
    const int buf = kt & 1;
    bf16x8 av[4], bv[4];
#pragma unroll
    for (int m = 0; m < 4; ++m) {
      int row = wr * 64 + m * 16 + c16;
      av[m] = ldsv(&sA[buf][row * 32 + (g ^ (row & 3)) * 8]);
    }
#pragma unroll
    for (int n = 0; n < 4; ++n) {
      int row = wc * 64 + n * 16 + c16;
      bv[n] = ldsv(&sB[buf][row * 32 + (g ^ (row & 3)) * 8]);
    }
#pragma unroll
    for (int m = 0; m < 4; ++m)
#pragma unroll
      for (int n = 0; n < 4; ++n)
        acc[m][n] = __builtin_amdgcn_mfma_f32_16x16x32_bf16(av[m], bv[n], acc[m][n], 0, 0, 0);
    __syncthreads();
  }

  const int orow = brow + wr * 64, ocol = bcol + wc * 64;
  if (Cb != nullptr) {
#pragma unroll
    for (int m = 0; m < 4; ++m)
#pragma unroll
      for (int n = 0; n < 4; ++n)
#pragma unroll
        for (int jj = 0; jj < 4; ++jj)
          Cb[(size_t)(orow + m * 16 + g * 4 + jj) * ldc + ocol + n * 16 + c16] =
              f2b(acc[m][n][jj]);
  } else {
#pragma unroll
    for (int m = 0; m < 4; ++m)
#pragma unroll
      for (int n = 0; n < 4; ++n)
#pragma unroll
        for (int jj = 0; jj < 4; ++jj)
          Cf[(size_t)(orow + m * 16 + g * 4 + jj) * ldc + ocol + n * 16 + c16] =
              acc[m][n][jj];
  }
}

// --------------------------- flash attention -------------------------------
// grid (16 qtiles, 16 b*h). block 256 = 4 waves, wave owns 32 q-rows.
// qkv: [4096][3072] bf16 (q|k|v each [.][h*128+d]).  outb: [4096][1024] bf16.
__global__ __launch_bounds__(256, 2) void k_attn(
    const unsigned short* __restrict__ qkv,
    const float* __restrict__ head_scales,
    unsigned short* __restrict__ outb) {
  __shared__ unsigned short sK[64 * 128];   // K tile, 256B rows, XOR-swizzled
  __shared__ unsigned short sVt[128 * 66];  // V^T tile [d][j], pitch 66
  __shared__ unsigned short sP[4][32 * 72]; // per-wave P tile, pitch 72
  __shared__ float sKp[64];

  const int t = threadIdx.x;
  const int lane = t & 63, wave = t >> 6;
  const int g = lane >> 4, c16 = lane & 15;
  const int qt = blockIdx.x;
  const int bh = blockIdx.y;
  const int b = bh >> 3, h = bh & 7;
  const float hs = head_scales[h];
  const float sx = (h & 4) ? 1.f : -1.f;
  const float sy = (h & 2) ? 1.f : -1.f;
  const float sz = (h & 1) ? 1.f : -1.f;

  const int q0 = qt * 128 + wave * 32;
  const size_t rowbase = (size_t)b * kT;

  // Q fragments in registers: rows m*16+c16, k = ks*32 + g*8 .. +7
  bf16x8 aq[2][4];
#pragma unroll
  for (int m = 0; m < 2; ++m)
#pragma unroll
    for (int ks = 0; ks < 4; ++ks) {
      int r = q0 + m * 16 + c16;
      aq[m][ks] = __builtin_bit_cast(bf16x8,
          *(const u16x8*)&qkv[(rowbase + r) * kN3 + h * kHD + ks * 32 + g * 8]);
    }
  // per-row q-projection (bias), folded with head scale
  float qp[2][4];
#pragma unroll
  for (int m = 0; m < 2; ++m)
#pragma unroll
    for (int jj = 0; jj < 4; ++jj) {
      int r = q0 + m * 16 + g * 4 + jj;
      const unsigned short* p = &qkv[(rowbase + r) * kN3 + h * kHD];
      qp[m][jj] = hs * kInvS3 * (sx * b2f(p[0]) + sy * b2f(p[1]) + sz * b2f(p[2]));
    }

  float mrow[2][4], lrow[2][4];
  f32x4 oacc[2][8];
#pragma unroll
  for (int m = 0; m < 2; ++m) {
#pragma unroll
    for (int jj = 0; jj < 4; ++jj) { mrow[m][jj] = -__builtin_inff(); lrow[m][jj] = 0.f; }
#pragma unroll
    for (int dn = 0; dn < 8; ++dn) oacc[m][dn] = 0.f;
  }

  const int nkv = 2 * qt + 2;
  const int wave_last = q0 + 31;
  for (int jt = 0; jt < nkv; ++jt) {
    const int j0 = jt * 64;
    __syncthreads();                       // prior reads done before restaging
    // --- stage K tile (async, swizzled) ---
#pragma unroll
    for (int is = 0; is < 4; ++is) {
      int row = is * 16 + (t >> 4);
      int gp = t & 15;
      int gs = (gp & 8) | ((gp ^ (row & 7)) & 7);
      gll16(&qkv[(rowbase + j0 + row) * kN3 + kC + h * kHD + gs * 8],
            &sK[is * 2048 + wave * 512]);
    }
    // --- stage V transposed (reg path; lane = kv row -> conflict-free writes) ---
#pragma unroll
    for (int it = 0; it < 4; ++it) {
      int dg = wave + it * 4;
      u16x8 v = *(const u16x8*)&qkv[(rowbase + j0 + lane) * kN3 + 2 * kC + h * kHD + dg * 8];
#pragma unroll
      for (int e = 0; e < 8; ++e) sVt[(dg * 8 + e) * 66 + lane] = v[e];
    }
    // --- k-projection for bias ---
    if (t < 64) {
      const unsigned short* p = &qkv[(rowbase + j0 + t) * kN3 + kC + h * kHD];
      sKp[t] = kInvS3 * (sx * b2f(p[0]) + sy * b2f(p[1]) + sz * b2f(p[2]));
    }
    __syncthreads();

    if (j0 <= wave_last) {                 // wave has unmasked work in this tile
      // ---- S = Q K^T ----
      f32x4 s[2][4];
#pragma unroll
      for (int m = 0; m < 2; ++m)
#pragma unroll
        for (int n = 0; n < 4; ++n) s[m][n] = 0.f;
#pragma unroll
      for (int ks = 0; ks < 4; ++ks) {
        bf16x8 kb[4];
#pragma unroll
        for (int n = 0; n < 4; ++n) {
          int j = n * 16 + c16;
          int gp = ks * 4 + g;
          int gp2 = (gp & 8) | ((gp ^ (j & 7)) & 7);
          kb[n] = ldsv(&sK[j * 128 + gp2 * 8]);
        }
#pragma unroll
        for (int m = 0; m < 2; ++m)
#pragma unroll
          for (int n = 0; n < 4; ++n)
            s[m][n] = __builtin_amdgcn_mfma_f32_16x16x32_bf16(aq[m][ks], kb[n], s[m][n], 0, 0, 0);
      }

      float kpv[4];
#pragma unroll
      for (int n = 0; n < 4; ++n) kpv[n] = sKp[n * 16 + c16];

      // ---- scale + bias + causal mask + online softmax ----
#pragma unroll
      for (int m = 0; m < 2; ++m) {
#pragma unroll
        for (int jj = 0; jj < 4; ++jj) {
          const int r = q0 + m * 16 + g * 4 + jj;
          const float qb = qp[m][jj];
          float sv[4];
          float vmax = -__builtin_inff();
#pragma unroll
          for (int n = 0; n < 4; ++n) {
            float xv = s[m][n][jj] * kScale + qb * kpv[n];
            int c = j0 + n * 16 + c16;
            xv = (c <= r) ? xv : -__builtin_inff();
            sv[n] = xv;
            vmax = fmaxf(vmax, xv);
          }
#pragma unroll
          for (int off = 1; off < 16; off <<= 1)
            vmax = fmaxf(vmax, __shfl_xor(vmax, off, 64));
          const float mold = mrow[m][jj];
          const float mnew = fmaxf(mold, vmax);
          const float alpha = exp2f((mold - mnew) * kL2E);
#pragma unroll
          for (int dn = 0; dn < 8; ++dn) oacc[m][dn][jj] *= alpha;
          float ls = 0.f;
#pragma unroll
          for (int n = 0; n < 4; ++n) {
            float pv = exp2f((sv[n] - mnew) * kL2E);
            ls += pv;
            sP[wave][(m * 16 + g * 4 + jj) * 72 + n * 16 + c16] = f2b(pv);
          }
          lrow[m][jj] = lrow[m][jj] * alpha + ls;   // per-lane partial row sum
          mrow[m][jj] = mnew;
        }
      }

      // ---- O += P V ----
#pragma unroll
      for (int ks2 = 0; ks2 < 2; ++ks2) {
        bf16x8 pa[2];
#pragma unroll
        for (int m = 0; m < 2; ++m)
          pa[m] = ldsv(&sP[wave][(m * 16 + c16) * 72 + ks2 * 32 + g * 8]);
#pragma unroll
        for (int dn = 0; dn < 8; ++dn) {
          bf16x8 vb = ldsv(&sVt[(dn * 16 + c16) * 66 + ks2 * 32 + g * 8]);
#pragma unroll
          for (int m = 0; m < 2; ++m)
            oacc[m][dn] = __builtin_amdgcn_mfma_f32_16x16x32_bf16(pa[m], vb, oacc[m][dn], 0, 0, 0);
        }
      }
    }
  }

  // ---- normalize and store ----
  float rinv[2][4];
#pragma unroll
  for (int m = 0; m < 2; ++m)
#pragma unroll
    for (int jj = 0; jj < 4; ++jj) {
      float lt = lrow[m][jj];
#pragma unroll
      for (int off = 1; off < 16; off <<= 1) lt += __shfl_xor(lt, off, 64);
      rinv[m][jj] = 1.0f / lt;
    }
#pragma unroll
  for (int m = 0; m < 2; ++m)
#pragma unroll
    for (int dn = 0; dn < 8; ++dn)
#pragma unroll
      for (int jj = 0; jj < 4; ++jj) {
        int r = q0 + m * 16 + g * 4 + jj;
        outb[(rowbase + r) * kC + h * kHD + dn * 16 + c16] =
            f2b(oacc[m][dn][jj] * rinv[m][jj]);
      }
}

// ---------------------------------------------------------------------------
extern "C" void kernel_launch(void* const* d_in, const int* in_sizes, int n_in,
                              void* d_out, int out_size, void* d_ws, size_t ws_size,
                              hipStream_t stream) {
  const float* x    = (const float*)d_in[0];
  const float* wqkv = (const float*)d_in[1];
  const float* wout = (const float*)d_in[2];
  const float* hsc  = (const float*)d_in[3];
  char* ws = (char*)d_ws;
  // workspace layout (bytes): xb 8M | wqkvT 6M | woutT 2M | qkv 24M | attn 8M  (~48MB)
  unsigned short* xb    = (unsigned short*)(ws);
  unsigned short* wqkvT = (unsigned short*)(ws + 8388608);
  unsigned short* woutT = (unsigned short*)(ws + 14680064);
  unsigned short* qkvb  = (unsigned short*)(ws + 16777216);
  unsigned short* attnb = (unsigned short*)(ws + 41943040);
  float* out = (float*)d_out;

  k_cvt<<<dim3(4096), dim3(256), 0, stream>>>(x, xb, kM * kC / 4);
  k_tc<<<dim3(48, 16), dim3(256), 0, stream>>>(wqkv, wqkvT, kC, kN3);
  k_tc<<<dim3(16, 16), dim3(256), 0, stream>>>(wout, woutT, kC, kC);
  k_gemm<<<dim3(32, 24), dim3(256), 0, stream>>>(xb, wqkvT, qkvb, nullptr, kM, kN3, kC, kN3);
  k_attn<<<dim3(16, 16), dim3(256), 0, stream>>>(qkvb, hsc, attnb);
  k_gemm<<<dim3(32, 8), dim3(256), 0, stream>>>(attnb, woutT, nullptr, out, kM, kC, kC, kC);
}

// Round 2
// 184.948 us; speedup vs baseline: 1.4431x; 1.4431x over previous
//
#include <hip/hip_runtime.h>
#include <hip/hip_bf16.h>
#include <cstdint>
#include <cstddef>

// ---------------------------------------------------------------------------
// YiJingAttention: x[B,T,C] -> qkv -> causal attn (+rank-1 trigram bias) -> out
// B=2 T=2048 C=1024 H=8 hd=128. All internal matmuls in bf16 MFMA, f32 accum.
// ---------------------------------------------------------------------------

namespace {
constexpr int kB = 2, kT = 2048, kC = 1024, kHD = 128;
constexpr int kM = kB * kT;   // 4096 rows
constexpr int kN3 = 3 * kC;   // 3072
constexpr float kScale = 0.08838834764831845f;   // 1/sqrt(128)
constexpr float kInvS3 = 0.57735026918962576f;   // 1/sqrt(3)
constexpr float kL2E  = 1.4426950408889634f;     // log2(e)
}

typedef __bf16 bf16x8 __attribute__((ext_vector_type(8)));
typedef float f32x4 __attribute__((ext_vector_type(4)));
typedef unsigned short u16x8 __attribute__((ext_vector_type(8)));
typedef unsigned short u16x4 __attribute__((ext_vector_type(4)));

__device__ __forceinline__ unsigned short f2b(float f) {
  return __builtin_bit_cast(unsigned short, (__bf16)f);
}
__device__ __forceinline__ float b2f(unsigned short u) {
  return (float)__builtin_bit_cast(__bf16, u);
}
// async global->LDS, 16B per lane. lds must be wave-uniform base (HW adds lane*16).
__device__ __forceinline__ void gll16(const void* g, void* lds) {
  __builtin_amdgcn_global_load_lds(
      (const __attribute__((address_space(1))) unsigned int*)g,
      (__attribute__((address_space(3))) unsigned int*)lds, 16, 0, 0);
}
__device__ __forceinline__ bf16x8 ldsv(const unsigned short* p) {
  return __builtin_bit_cast(bf16x8, *(const u16x8*)p);
}

// -------------------------- fp32 -> bf16 cast ------------------------------
__global__ void k_cvt(const float* __restrict__ in, unsigned short* __restrict__ out, int n4) {
  int i = blockIdx.x * 256 + threadIdx.x;
  if (i >= n4) return;
  float4 v = ((const float4*)in)[i];
  u16x4 o = { f2b(v.x), f2b(v.y), f2b(v.z), f2b(v.w) };
  ((u16x4*)out)[i] = o;
}

// ------------------- transpose + cast: in[R][Cin]f32 -> out[Cin][R]bf16 ----
__global__ void k_tc(const float* __restrict__ in, unsigned short* __restrict__ out,
                     int R, int Cin) {
  __shared__ float tile[64][65];
  const int t = threadIdx.x;
  const int r0 = blockIdx.y * 64, c0 = blockIdx.x * 64;
  const int tr = t >> 4, tc4 = (t & 15) * 4;
#pragma unroll
  for (int rr = 0; rr < 4; ++rr) {
    int r = tr + rr * 16;
    float4 v = *(const float4*)&in[(size_t)(r0 + r) * Cin + c0 + tc4];
    tile[r][tc4 + 0] = v.x; tile[r][tc4 + 1] = v.y;
    tile[r][tc4 + 2] = v.z; tile[r][tc4 + 3] = v.w;
  }
  __syncthreads();
#pragma unroll
  for (int rr = 0; rr < 4; ++rr) {
    int c = tr + rr * 16;
    u16x4 o = { f2b(tile[tc4 + 0][c]), f2b(tile[tc4 + 1][c]),
                f2b(tile[tc4 + 2][c]), f2b(tile[tc4 + 3][c]) };
    *(u16x4*)&out[(size_t)(c0 + c) * R + r0 + tc4] = o;
  }
}

// ----------------- 128x128 bf16 MFMA GEMM, Bt is [N][K] --------------------
// C = A[M,K] @ Bt^T. Writes bf16 (Cb) or f32 (Cf).
__global__ __launch_bounds__(256, 2) void k_gemm(
    const unsigned short* __restrict__ A,
    const unsigned short* __restrict__ Bt,
    unsigned short* __restrict__ Cb,
    float* __restrict__ Cf,
    int M, int N, int K, int ldc) {
  __shared__ unsigned short sA[2][4096];   // 128 rows x 32 k (swizzled groups)
  __shared__ unsigned short sB[2][4096];
  const int t = threadIdx.x;
  const int lane = t & 63, wave = t >> 6;
  const int g = lane >> 4, c16 = lane & 15;
  const int wr = wave >> 1, wc = wave & 1;
  const int brow = blockIdx.x * 128, bcol = blockIdx.y * 128;
  const int NT = K >> 5;

  f32x4 acc[4][4];
#pragma unroll
  for (int m = 0; m < 4; ++m)
#pragma unroll
    for (int n = 0; n < 4; ++n) acc[m][n] = 0.f;

  auto stage = [&](int buf, int kt) {
    const int k0 = kt * 32;
#pragma unroll
    for (int is = 0; is < 2; ++is) {
      int row = is * 64 + (t >> 2);
      int gs = (t & 3) ^ (row & 3);          // pre-swizzled source group
      gll16(&A[(size_t)(brow + row) * K + k0 + gs * 8], &sA[buf][is * 2048 + wave * 512]);
      gll16(&Bt[(size_t)(bcol + row) * K + k0 + gs * 8], &sB[buf][is * 2048 + wave * 512]);
    }
  };

  stage(0, 0);
  __syncthreads();
  for (int kt = 0; kt < NT; ++kt) {
    if (kt + 1 < NT) stage((kt + 1) & 1, kt + 1);
    const int buf = kt & 1;
    bf16x8 av[4], bv[4];
#pragma unroll
    for (int m = 0; m < 4; ++m) {
      int row = wr * 64 + m * 16 + c16;
      av[m] = ldsv(&sA[buf][row * 32 + (g ^ (row & 3)) * 8]);
    }
#pragma unroll
    for (int n = 0; n < 4; ++n) {
      int row = wc * 64 + n * 16 + c16;
      bv[n] = ldsv(&sB[buf][row * 32 + (g ^ (row & 3)) * 8]);
    }
    __builtin_amdgcn_s_setprio(1);
#pragma unroll
    for (int m = 0; m < 4; ++m)
#pragma unroll
      for (int n = 0; n < 4; ++n)
        acc[m][n] = __builtin_amdgcn_mfma_f32_16x16x32_bf16(av[m], bv[n], acc[m][n], 0, 0, 0);
    __builtin_amdgcn_s_setprio(0);
    __syncthreads();
  }

  const int orow = brow + wr * 64, ocol = bcol + wc * 64;
  if (Cb != nullptr) {
#pragma unroll
    for (int m = 0; m < 4; ++m)
#pragma unroll
      for (int n = 0; n < 4; ++n)
#pragma unroll
        for (int jj = 0; jj < 4; ++jj)
          Cb[(size_t)(orow + m * 16 + g * 4 + jj) * ldc + ocol + n * 16 + c16] =
              f2b(acc[m][n][jj]);
  } else {
#pragma unroll
    for (int m = 0; m < 4; ++m)
#pragma unroll
      for (int n = 0; n < 4; ++n)
#pragma unroll
        for (int jj = 0; jj < 4; ++jj)
          Cf[(size_t)(orow + m * 16 + g * 4 + jj) * ldc + ocol + n * 16 + c16] =
              acc[m][n][jj];
  }
}

// --------------------------- flash attention -------------------------------
// grid (16 qtiles, 16 b*h). block 512 = 8 waves, wave owns 16 q-rows.
// qkv: [4096][3072] bf16 (q|k|v each [.][h*128+d]).  outb: [4096][1024] bf16.
__global__ __launch_bounds__(512, 2) void k_attn(
    const unsigned short* __restrict__ qkv,
    const float* __restrict__ head_scales,
    unsigned short* __restrict__ outb) {
  __shared__ unsigned short sK[64 * 128];   // K tile, 256B rows, XOR-swizzled
  __shared__ unsigned short sVt[128 * 72];  // V^T tile [d][j], pitch 72 (aligned+cf)
  __shared__ unsigned short sP[8][16 * 72]; // per-wave P tile, pitch 72
  __shared__ float sKp[64];

  const int t = threadIdx.x;
  const int lane = t & 63, wave = t >> 6;
  const int g = lane >> 4, c16 = lane & 15;
  const int qt = 15 - blockIdx.x;          // heavy tiles dispatch first
  const int bh = blockIdx.y;
  const int b = bh >> 3, h = bh & 7;
  const float hs = head_scales[h];
  const float sx = (h & 4) ? 1.f : -1.f;
  const float sy = (h & 2) ? 1.f : -1.f;
  const float sz = (h & 1) ? 1.f : -1.f;

  const int q0 = qt * 128 + wave * 16;     // this wave's 16 q-rows
  const size_t rowbase = (size_t)b * kT;

  // Q fragments in registers: rows c16, k = ks*32 + g*8 .. +7
  bf16x8 aq[4];
#pragma unroll
  for (int ks = 0; ks < 4; ++ks) {
    int r = q0 + c16;
    aq[ks] = __builtin_bit_cast(bf16x8,
        *(const u16x8*)&qkv[(rowbase + r) * kN3 + h * kHD + ks * 32 + g * 8]);
  }
  // per-row q-projection (bias), folded with head scale
  float qp[4];
#pragma unroll
  for (int jj = 0; jj < 4; ++jj) {
    int r = q0 + g * 4 + jj;
    const unsigned short* p = &qkv[(rowbase + r) * kN3 + h * kHD];
    qp[jj] = hs * kInvS3 * (sx * b2f(p[0]) + sy * b2f(p[1]) + sz * b2f(p[2]));
  }

  float mrow[4], lrow[4];
  f32x4 oacc[8];
#pragma unroll
  for (int jj = 0; jj < 4; ++jj) { mrow[jj] = -__builtin_inff(); lrow[jj] = 0.f; }
#pragma unroll
  for (int dn = 0; dn < 8; ++dn) oacc[dn] = 0.f;

  const int nkv = 2 * qt + 2;
  const int wave_last = q0 + 15;
  for (int jt = 0; jt < nkv; ++jt) {
    const int j0 = jt * 64;
    __syncthreads();                       // prior reads done before restaging
    // --- stage K tile (async, swizzled). 512 threads cover 64x128 bf16 ---
#pragma unroll
    for (int is = 0; is < 2; ++is) {
      int row = is * 32 + (t >> 4);
      int gp = t & 15;
      int gs = (gp & 8) | ((gp ^ (row & 7)) & 7);
      gll16(&qkv[(rowbase + j0 + row) * kN3 + kC + h * kHD + gs * 8],
            &sK[is * 4096 + wave * 512]);
    }
    // --- stage V transposed (reg path; lane = kv row -> conflict-free writes) ---
#pragma unroll
    for (int it = 0; it < 2; ++it) {
      int idx = it * 512 + t;
      int dg = idx >> 6, row = idx & 63;
      u16x8 v = *(const u16x8*)&qkv[(rowbase + j0 + row) * kN3 + 2 * kC + h * kHD + dg * 8];
#pragma unroll
      for (int e = 0; e < 8; ++e) sVt[(dg * 8 + e) * 72 + row] = v[e];
    }
    // --- k-projection for bias ---
    if (t < 64) {
      const unsigned short* p = &qkv[(rowbase + j0 + t) * kN3 + kC + h * kHD];
      sKp[t] = kInvS3 * (sx * b2f(p[0]) + sy * b2f(p[1]) + sz * b2f(p[2]));
    }
    __syncthreads();

    if (j0 <= wave_last) {                 // wave has unmasked work in this tile
      // ---- S = Q K^T ----
      f32x4 s[4];
#pragma unroll
      for (int n = 0; n < 4; ++n) s[n] = 0.f;
#pragma unroll
      for (int ks = 0; ks < 4; ++ks) {
        bf16x8 kb[4];
#pragma unroll
        for (int n = 0; n < 4; ++n) {
          int j = n * 16 + c16;
          int gp = ks * 4 + g;
          int gp2 = (gp & 8) | ((gp ^ (j & 7)) & 7);
          kb[n] = ldsv(&sK[j * 128 + gp2 * 8]);
        }
        __builtin_amdgcn_s_setprio(1);
#pragma unroll
        for (int n = 0; n < 4; ++n)
          s[n] = __builtin_amdgcn_mfma_f32_16x16x32_bf16(aq[ks], kb[n], s[n], 0, 0, 0);
        __builtin_amdgcn_s_setprio(0);
      }

      float kpv[4];
#pragma unroll
      for (int n = 0; n < 4; ++n) kpv[n] = sKp[n * 16 + c16];

      // ---- scale + bias + causal mask + online softmax ----
#pragma unroll
      for (int jj = 0; jj < 4; ++jj) {
        const int r = q0 + g * 4 + jj;
        const float qb = qp[jj];
        float sv[4];
        float vmax = -__builtin_inff();
#pragma unroll
        for (int n = 0; n < 4; ++n) {
          float xv = s[n][jj] * kScale + qb * kpv[n];
          int c = j0 + n * 16 + c16;
          xv = (c <= r) ? xv : -__builtin_inff();
          sv[n] = xv;
          vmax = fmaxf(vmax, xv);
        }
#pragma unroll
        for (int off = 1; off < 16; off <<= 1)
          vmax = fmaxf(vmax, __shfl_xor(vmax, off, 64));
        const float mold = mrow[jj];
        const float mnew = fmaxf(mold, vmax);
        const float alpha = exp2f((mold - mnew) * kL2E);
#pragma unroll
        for (int dn = 0; dn < 8; ++dn) oacc[dn][jj] *= alpha;
        float ls = 0.f;
#pragma unroll
        for (int n = 0; n < 4; ++n) {
          float pv = exp2f((sv[n] - mnew) * kL2E);
          ls += pv;
          sP[wave][(g * 4 + jj) * 72 + n * 16 + c16] = f2b(pv);
        }
        lrow[jj] = lrow[jj] * alpha + ls;   // per-lane partial row sum
        mrow[jj] = mnew;
      }

      // ---- O += P V ----
#pragma unroll
      for (int ks2 = 0; ks2 < 2; ++ks2) {
        bf16x8 pa = ldsv(&sP[wave][c16 * 72 + ks2 * 32 + g * 8]);
        __builtin_amdgcn_s_setprio(1);
#pragma unroll
        for (int dn = 0; dn < 8; ++dn) {
          bf16x8 vb = ldsv(&sVt[(dn * 16 + c16) * 72 + ks2 * 32 + g * 8]);
          oacc[dn] = __builtin_amdgcn_mfma_f32_16x16x32_bf16(pa, vb, oacc[dn], 0, 0, 0);
        }
        __builtin_amdgcn_s_setprio(0);
      }
    }
  }

  // ---- normalize and store ----
  float rinv[4];
#pragma unroll
  for (int jj = 0; jj < 4; ++jj) {
    float lt = lrow[jj];
#pragma unroll
    for (int off = 1; off < 16; off <<= 1) lt += __shfl_xor(lt, off, 64);
    rinv[jj] = 1.0f / lt;
  }
#pragma unroll
  for (int dn = 0; dn < 8; ++dn)
#pragma unroll
    for (int jj = 0; jj < 4; ++jj) {
      int r = q0 + g * 4 + jj;
      outb[(rowbase + r) * kC + h * kHD + dn * 16 + c16] =
          f2b(oacc[dn][jj] * rinv[jj]);
    }
}

// ---------------------------------------------------------------------------
extern "C" void kernel_launch(void* const* d_in, const int* in_sizes, int n_in,
                              void* d_out, int out_size, void* d_ws, size_t ws_size,
                              hipStream_t stream) {
  const float* x    = (const float*)d_in[0];
  const float* wqkv = (const float*)d_in[1];
  const float* wout = (const float*)d_in[2];
  const float* hsc  = (const float*)d_in[3];
  char* ws = (char*)d_ws;
  // workspace layout (bytes): xb 8M | wqkvT 6M | woutT 2M | qkv 24M | attn 8M  (~48MB)
  unsigned short* xb    = (unsigned short*)(ws);
  unsigned short* wqkvT = (unsigned short*)(ws + 8388608);
  unsigned short* woutT = (unsigned short*)(ws + 14680064);
  unsigned short* qkvb  = (unsigned short*)(ws + 16777216);
  unsigned short* attnb = (unsigned short*)(ws + 41943040);
  float* out = (float*)d_out;

  k_cvt<<<dim3(4096), dim3(256), 0, stream>>>(x, xb, kM * kC / 4);
  k_tc<<<dim3(48, 16), dim3(256), 0, stream>>>(wqkv, wqkvT, kC, kN3);
  k_tc<<<dim3(16, 16), dim3(256), 0, stream>>>(wout, woutT, kC, kC);
  k_gemm<<<dim3(32, 24), dim3(256), 0, stream>>>(xb, wqkvT, qkvb, nullptr, kM, kN3, kC, kN3);
  k_attn<<<dim3(16, 16), dim3(512), 0, stream>>>(qkvb, hsc, attnb);
  k_gemm<<<dim3(32, 8), dim3(256), 0, stream>>>(attnb, woutT, nullptr, out, kM, kC, kC, kC);
}